// Round 10
// baseline (162.413 us; speedup 1.0000x reference)
//
#include <hip/hip_runtime.h>

typedef __attribute__((ext_vector_type(8))) short short8;
typedef __attribute__((ext_vector_type(4))) float f32x4;

#define INF 4096

#define AS1 __attribute__((address_space(1)))
#define AS3 __attribute__((address_space(3)))

__device__ __forceinline__ unsigned short f2bf(float f) {
    unsigned int u = __float_as_uint(f);
    u += 0x7FFFu + ((u >> 16) & 1u);
    return (unsigned short)(u >> 16);
}

__device__ __forceinline__ void gl_lds16(const unsigned short* g, void* l) {
    __builtin_amdgcn_global_load_lds((const AS1 void*)g, (AS3 void*)l, 16, 0, 0);
}

// XOR byte bits {4,5,6} with bits {7,8,9}: involution, 16B-preserving.
// For [128][64]bf16 regions (128B rows): fragment reads 0-conflict (R8/R9).
__device__ __forceinline__ int swz7(int b) { return b ^ ((b >> 3) & 0x70); }

#define BAR()   __builtin_amdgcn_s_barrier()
#define SB0()   __builtin_amdgcn_sched_barrier(0)

// ---------------- prepass: fp32 -> bf16 for x and hw ----------------
__global__ __launch_bounds__(256)
void cvt_bf16(const float* __restrict__ x, const float* __restrict__ hw,
              unsigned short* __restrict__ xb, unsigned short* __restrict__ wb)
{
    const long long NX = 8192LL * 4096;
    const long long NW = 5LL * 16 * 256 * 256;
    const long long total8 = (NX + NW) / 8;
    for (long long i = (long long)blockIdx.x * 256 + threadIdx.x; i < total8;
         i += (long long)gridDim.x * 256) {
        long long e = i * 8;
        const float* src;
        unsigned short* dst;
        long long off;
        if (e < NX) { src = x;  dst = xb; off = e; }
        else        { src = hw; dst = wb; off = e - NX; }
        float4 f0 = *(const float4*)(src + off);
        float4 f1 = *(const float4*)(src + off + 4);
        ushort4 u0, u1;
        u0.x = f2bf(f0.x); u0.y = f2bf(f0.y); u0.z = f2bf(f0.z); u0.w = f2bf(f0.w);
        u1.x = f2bf(f1.x); u1.y = f2bf(f1.y); u1.z = f2bf(f1.z); u1.w = f2bf(f1.w);
        *(ushort4*)(dst + off)     = u0;
        *(ushort4*)(dst + off + 4) = u1;
    }
}

// ======== main GEMM: 128x256 tile, 4 waves, BK=64, B direct from L2 ========
// A: 3-buffer LDS [128][64]bf16 swz7 (16KB each, 48KB total) staged via
// global_load_lds, 2 tiles prefetch depth. B: per-lane contiguous 16B
// global loads (wb is K-contiguous) straight into registers -- no LDS.
// Sync: B loads issued BEFORE the A-stage each iter, so the compiler's
// counted vmcnt waits for fb retire stage(kt) but keep stage(kt+1),(kt+2)
// in flight. One barrier per K-tile. 2 blocks/CU (LDS 96KB, 8 waves).
__global__ __launch_bounds__(256, 2)
void hcl_gbd(const unsigned short* __restrict__ xb,
             const unsigned short* __restrict__ wb,
             const float* __restrict__ hb,
             float* __restrict__ out)
{
    __shared__ char lds[3 * 16384];

    const int tid  = threadIdx.x;        // 0..255
    const int lane = tid & 63;
    const int wave = tid >> 6;           // 0..3 = n-quarter of 256-col tile
    const int ln15 = lane & 15;
    const int hi   = lane >> 4;          // 0..3

    const int bm0 = blockIdx.x * 128;
    const int p   = blockIdx.y;          // 0..15

    // A fragment byte offsets in a 16KB buffer (ks=1 via ^64, verified R8/R9)
    int offA[8];
    #pragma unroll
    for (int mf = 0; mf < 8; ++mf)
        offA[mf] = swz7((mf * 16 + ln15) * 128 + hi * 16);

    // staging source geometry: inst j writes phys = j*4096 + tid*16 (linear);
    // logical = swz7(phys) -> (row, col) of the [128][64] tile
    int srow[4], skcol[4];
    #pragma unroll
    for (int j = 0; j < 4; ++j) {
        int L = swz7(j * 4096 + tid * 16);
        srow[j]  = L >> 7;
        skcol[j] = (L & 127) >> 1;
    }

    // B per-lane base: col = wave*64 + nf*16 + ln15 (nf via +nf*4096 elems),
    // k-offset hi*8 (+ks*32); per tile add (t*16+s)*65536 + (kt&3)*64.
    const unsigned short* gB = wb + (size_t)(wave * 64 + ln15) * 256 + hi * 8;

    f32x4 acc[8][4] = {};

    auto STAGE = [&](int kt) {
        if (kt >= 20) return;
        const int t  = kt >> 2;
        const int s  = p ^ ((1 << t) >> 1);
        const int k0 = (kt & 3) * 64;
        const unsigned short* ga = xb + (size_t)bm0 * INF + s * 256 + k0;
        char* dst = lds + (kt % 3) * 16384 + tid * 16;
        gl_lds16(ga + (size_t)srow[0] * INF + skcol[0], dst);
        gl_lds16(ga + (size_t)srow[1] * INF + skcol[1], dst + 4096);
        gl_lds16(ga + (size_t)srow[2] * INF + skcol[2], dst + 8192);
        gl_lds16(ga + (size_t)srow[3] * INF + skcol[3], dst + 12288);
    };

    short8 fa[8], fb[8];
    auto LDA = [&](int qm, const char* L) {   // rows qm*64..+63, K=64
        #pragma unroll
        for (int m = 0; m < 4; ++m) {
            fa[m * 2 + 0] = *(const short8*)(L + offA[qm * 4 + m]);
            fa[m * 2 + 1] = *(const short8*)(L + (offA[qm * 4 + m] ^ 64));
        }
    };
    auto MM0 = [&](int qm) {                  // cols 0..31 (fb[0..3])
        __builtin_amdgcn_s_setprio(1);
        #pragma unroll
        for (int m = 0; m < 4; ++m)
            #pragma unroll
            for (int n = 0; n < 2; ++n)
                #pragma unroll
                for (int ks = 0; ks < 2; ++ks)
                    acc[qm * 4 + m][n] = __builtin_amdgcn_mfma_f32_16x16x32_bf16(
                        fa[m * 2 + ks], fb[n * 2 + ks], acc[qm * 4 + m][n], 0, 0, 0);
        __builtin_amdgcn_s_setprio(0);
    };
    auto MM1 = [&](int qm) {                  // cols 32..63 (fb[4..7])
        __builtin_amdgcn_s_setprio(1);
        #pragma unroll
        for (int m = 0; m < 4; ++m)
            #pragma unroll
            for (int n = 0; n < 2; ++n)
                #pragma unroll
                for (int ks = 0; ks < 2; ++ks)
                    acc[qm * 4 + m][2 + n] = __builtin_amdgcn_mfma_f32_16x16x32_bf16(
                        fa[m * 2 + ks], fb[4 + n * 2 + ks], acc[qm * 4 + m][2 + n], 0, 0, 0);
        __builtin_amdgcn_s_setprio(0);
    };

    // prologue: A tiles 0,1 in flight; land tile 0; all-waves fence
    STAGE(0); STAGE(1);
    asm volatile("s_waitcnt vmcnt(4)" ::: "memory");
    BAR(); SB0();

    for (int kt = 0; kt < 20; ++kt) {
        const int t = kt >> 2;
        const int s = p ^ ((1 << t) >> 1);
        const size_t tOff = ((size_t)(t * 16 + s) << 16) + (kt & 3) * 64;
        // B loads FIRST (oldest in vmcnt queue): fb waits then retire stage(kt)
        // but keep the younger stage(kt+1),(kt+2) in flight.
        #pragma unroll
        for (int nf = 0; nf < 4; ++nf)
            #pragma unroll
            for (int ks = 0; ks < 2; ++ks)
                fb[nf * 2 + ks] = *(const short8*)(gB + tOff + nf * 4096 + ks * 32);
        SB0();
        STAGE(kt + 2);
        SB0();
        const char* L = lds + (kt % 3) * 16384;
        LDA(0, L); MM0(0); MM1(0);
        LDA(1, L); MM0(1); MM1(1);
        BAR(); SB0();
    }

    // epilogue: C/D layout col = lane&15, row = (lane>>4)*4 + r  [R5-verified]
    const int col0 = p * 256 + wave * 64;
    #pragma unroll
    for (int nf = 0; nf < 4; ++nf) {
        const int col = col0 + nf * 16 + ln15;
        const float bias = hb[col];
        #pragma unroll
        for (int mf = 0; mf < 8; ++mf) {
            #pragma unroll
            for (int r = 0; r < 4; ++r) {
                const int row = bm0 + mf * 16 + hi * 4 + r;
                out[(size_t)row * 4096 + col] = acc[mf][nf][r] + bias;
            }
        }
    }
}

// ---------------- fallback (fused) if ws too small ----------------
__global__ __launch_bounds__(256)
void hcl_mfma_fused(const float* __restrict__ x,
                    const float* __restrict__ hw,
                    const float* __restrict__ hb,
                    float* __restrict__ out)
{
    __shared__ unsigned short As[128][32];
    __shared__ unsigned short Bs[128][32];

    const int tid  = threadIdx.x;
    const int lane = tid & 63;
    const int wave = tid >> 6;
    const int wr   = wave >> 1, wc = wave & 1;

    const int bm0 = blockIdx.x * 128;
    const int p   = blockIdx.y >> 1;
    const int nh  = blockIdx.y & 1;

    f32x4 acc[4][4] = {};

    const int srow = tid >> 3;
    const int scol = (tid & 7) * 4;

    #pragma unroll
    for (int t = 0; t < 5; ++t) {
        const int mask = (t == 0) ? 0 : (1 << (t - 1));
        const int s = p ^ mask;
        const float* xchunk = x  + (size_t)bm0 * INF + s * 256;
        const float* wchunk = hw + ((size_t)(t * 16 + s) * 256 + nh * 128) * 256;

        for (int k8 = 0; k8 < 8; ++k8) {
            const int kc = k8 * 32;
            #pragma unroll
            for (int i = 0; i < 4; ++i) {
                const int row = i * 32 + srow;
                float4 fa = *(const float4*)(xchunk + (size_t)row * INF + kc + scol);
                float4 fb = *(const float4*)(wchunk + (size_t)row * 256 + kc + scol);
                ushort4 ua, ub;
                ua.x = f2bf(fa.x); ua.y = f2bf(fa.y);
                ua.z = f2bf(fa.z); ua.w = f2bf(fa.w);
                ub.x = f2bf(fb.x); ub.y = f2bf(fb.y);
                ub.z = f2bf(fb.z); ub.w = f2bf(fb.w);
                *(ushort4*)&As[row][scol] = ua;
                *(ushort4*)&Bs[row][scol] = ub;
            }
            __syncthreads();

            short8 a[4], b[4];
            #pragma unroll
            for (int mi = 0; mi < 4; ++mi)
                a[mi] = *(const short8*)&As[wr * 64 + mi * 16 + (lane & 15)][(lane >> 4) * 8];
            #pragma unroll
            for (int nj = 0; nj < 4; ++nj)
                b[nj] = *(const short8*)&Bs[wc * 64 + nj * 16 + (lane & 15)][(lane >> 4) * 8];

            #pragma unroll
            for (int mi = 0; mi < 4; ++mi)
                #pragma unroll
                for (int nj = 0; nj < 4; ++nj)
                    acc[mi][nj] = __builtin_amdgcn_mfma_f32_16x16x32_bf16(
                        a[mi], b[nj], acc[mi][nj], 0, 0, 0);

            __syncthreads();
        }
    }

    const int col0 = p * 256 + nh * 128 + wc * 64;
    #pragma unroll
    for (int nj = 0; nj < 4; ++nj) {
        const int col = col0 + nj * 16 + (lane & 15);
        const float bias = hb[col];
        #pragma unroll
        for (int mi = 0; mi < 4; ++mi) {
            #pragma unroll
            for (int r = 0; r < 4; ++r) {
                const int row = bm0 + wr * 64 + mi * 16 + (lane >> 4) * 4 + r;
                out[(size_t)row * 4096 + col] = acc[mi][nj][r] + bias;
            }
        }
    }
}

extern "C" void kernel_launch(void* const* d_in, const int* in_sizes, int n_in,
                              void* d_out, int out_size, void* d_ws, size_t ws_size,
                              hipStream_t stream) {
    const float* x  = (const float*)d_in[0];   // [8192, 4096]
    const float* hw = (const float*)d_in[1];   // [5, 16, 256, 256]
    const float* hb = (const float*)d_in[2];   // [4096]
    float* out = (float*)d_out;                // [8192, 4096]

    const size_t NX = 8192ull * 4096;
    const size_t NW = 5ull * 16 * 256 * 256;
    const size_t need = (NX + NW) * sizeof(unsigned short);

    if (ws_size >= need) {
        unsigned short* xb = (unsigned short*)d_ws;
        unsigned short* wb = xb + NX;
        cvt_bf16<<<2048, 256, 0, stream>>>(x, hw, xb, wb);
        dim3 grid(8192 / 128, 16);
        hcl_gbd<<<grid, 256, 0, stream>>>(xb, wb, hb, out);
    } else {
        dim3 grid(8192 / 128, 32);
        hcl_mfma_fused<<<grid, 256, 0, stream>>>(x, hw, hb, out);
    }
}